// Round 4
// baseline (252.187 us; speedup 1.0000x reference)
//
#include <hip/hip_runtime.h>

#define DIMN 32
#define HD   32
#define FN   16
#define FE   8
#define NG   64
#define CAP  64      // bucket capacity (in-degree ~Poisson(16); fallback below)
#define NPW  2       // nodes per wave in K3
#define K3T  512     // threads per block in K3 (8 waves)
#define K3W  (K3T / 64)
#define K3NPB (K3W * NPW)   // 16 nodes per block

// K1: out = relu(x @ lin0_w^T + lin0_b); zero deg/aggfb/u/done.
__global__ __launch_bounds__(256) void k1_out(
    const float* __restrict__ x, const float* __restrict__ lin0_w,
    const float* __restrict__ lin0_b,
    float* __restrict__ outn, float* __restrict__ aggfb, float* __restrict__ u,
    int* __restrict__ deg, int* __restrict__ done, int N)
{
    const int gt = blockIdx.x * 256 + threadIdx.x;
    if (gt >= N * DIMN) return;
    const int n = gt >> 5, d = gt & 31;

    float s = lin0_b[d];
    const float* xr = x + (size_t)n * FN;
    const float* wr = lin0_w + d * FN;
    #pragma unroll
    for (int j = 0; j < FN; ++j) s = fmaf(xr[j], wr[j], s);
    outn[gt] = fmaxf(s, 0.f);

    aggfb[gt] = 0.f;
    if (d == 0) deg[n] = 0;
    if (gt < NG * HD) u[gt] = 0.f;
    if (gt == 0) *done = 0;
}

// Kb: bucket edges by destination: es[dst*CAP+pos] = {e, src}.
// Overflow (statistically never for Poisson(16) vs CAP=64): compute the message
// directly and atomicAdd into aggfb, which K3 adds before relu.
__global__ __launch_bounds__(256) void kb_bucket(
    const int* __restrict__ ei, const float* __restrict__ ea,
    const float* __restrict__ outn, const float* __restrict__ nn_w,
    const float* __restrict__ nn_b,
    int* __restrict__ deg, int2* __restrict__ es, float* __restrict__ aggfb, int E)
{
    const int e = blockIdx.x * 256 + threadIdx.x;
    if (e >= E) return;
    const int src = ei[e];
    const int dst = ei[E + e];
    const int pos = atomicAdd(&deg[dst], 1);
    if (pos < CAP) {
        es[(size_t)dst * CAP + pos] = make_int2(e, src);
    } else {
        float ef[FE];
        #pragma unroll
        for (int f = 0; f < FE; ++f) ef[f] = ea[(size_t)e * FE + f];
        for (int h = 0; h < HD; ++h) {
            float m = 0.f;
            for (int d = 0; d < DIMN; ++d) {
                float wdh = nn_b[d * HD + h];
                #pragma unroll
                for (int f = 0; f < FE; ++f)
                    wdh = fmaf(ef[f], nn_w[(d * HD + h) * FE + f], wdh);
                m = fmaf(outn[(size_t)src * DIMN + d], wdh, m);
            }
            atomicAdd(aggfb + (size_t)dst * HD + h, m);
        }
    }
}

// K3: per dst node, accumulate T[d,f] = sum_e out[src,d]*ea[e,f] in registers
// (lane l: d=l&31, f in 4p..4p+3, p=l>>5), stage T/S/out[n] in per-wave LDS,
// contract with LDS-transposed nn_w via broadcast reads (NO per-element shfl),
// root + relu + run-length pool into u. Last block computes the head.
__global__ __launch_bounds__(K3T) void k3_gather(
    const float* __restrict__ ea, const float* __restrict__ outn,
    const int2* __restrict__ es, const float* __restrict__ nn_w,
    const float* __restrict__ nn_b, const float* __restrict__ root_w,
    const float* __restrict__ conv_b, const int* __restrict__ deg,
    const float* __restrict__ aggfb, const int* __restrict__ batch,
    const float* __restrict__ lin1_w, const float* __restrict__ lin1_b,
    const float* __restrict__ lin2_w, const float* __restrict__ lin2_b,
    float* __restrict__ u, int* __restrict__ done, float* __restrict__ outp,
    int N, int nblocks)
{
    __shared__ float s_nnw2[DIMN * FE * HD];  // [(d*8+f)*32 + h]  32 KB
    __shared__ float s_nnb[DIMN * HD];        // [d*32 + h]         4 KB
    __shared__ float s_rw[DIMN * HD];         // [d*32 + h]         4 KB
    __shared__ float s_cb[HD];
    __shared__ float s_T[K3W * 256];          // per-wave T slot    8 KB
    __shared__ float s_S[K3W * 32];
    __shared__ float s_O[K3W * 32];
    __shared__ int   s_last;

    const int tid = threadIdx.x;
    for (int i = tid; i < DIMN * FE * HD; i += K3T) {
        const int d = i >> 8, rem = i & 255, hh = rem >> 3, f = rem & 7;
        s_nnw2[(d * 8 + f) * 32 + hh] = nn_w[i];   // nn_w[i] = nn_w[(d*32+hh)*8+f]
    }
    for (int i = tid; i < DIMN * HD; i += K3T) { s_nnb[i] = nn_b[i]; s_rw[i] = root_w[i]; }
    if (tid < HD) s_cb[tid] = conv_b[tid];
    __syncthreads();

    const int l = tid & 63;
    const int h = l & 31;
    const int p = l >> 5;
    const int w = tid >> 6;
    const int wid   = blockIdx.x * K3W + w;
    const int nbase = wid * NPW;

    float accp  = 0.f;
    int   g_cur = -1;

    for (int i = 0; i < NPW; ++i) {
        const int n = nbase + i;
        if (n >= N) break;                          // n wave-uniform -> whole wave exits
        const int nu = __builtin_amdgcn_readfirstlane(n);
        const int dn = min(deg[nu], CAP);           // uniform -> s_load
        const int2* ep = es + (size_t)nu * CAP;

        // Edge loop: uniform s_load of {e,src}; broadcast-line vector loads; 2-way ILP.
        float T0a = 0.f, T1a = 0.f, T2a = 0.f, T3a = 0.f, Sa = 0.f;
        float T0b = 0.f, T1b = 0.f, T2b = 0.f, T3b = 0.f, Sb = 0.f;
        int j = 0;
        for (; j + 2 <= dn; j += 2) {
            const int2 eA = ep[j];
            const int2 eB = ep[j + 1];
            const float4 wA = *(const float4*)(ea + (size_t)eA.x * FE + 4 * p);
            const float4 wB = *(const float4*)(ea + (size_t)eB.x * FE + 4 * p);
            const float  oA = outn[(size_t)eA.y * DIMN + h];
            const float  oB = outn[(size_t)eB.y * DIMN + h];
            Sa += oA;  Sb += oB;
            T0a = fmaf(oA, wA.x, T0a);  T1a = fmaf(oA, wA.y, T1a);
            T2a = fmaf(oA, wA.z, T2a);  T3a = fmaf(oA, wA.w, T3a);
            T0b = fmaf(oB, wB.x, T0b);  T1b = fmaf(oB, wB.y, T1b);
            T2b = fmaf(oB, wB.z, T2b);  T3b = fmaf(oB, wB.w, T3b);
        }
        if (j < dn) {
            const int2 eA = ep[j];
            const float4 wA = *(const float4*)(ea + (size_t)eA.x * FE + 4 * p);
            const float  oA = outn[(size_t)eA.y * DIMN + h];
            Sa += oA;
            T0a = fmaf(oA, wA.x, T0a);  T1a = fmaf(oA, wA.y, T1a);
            T2a = fmaf(oA, wA.z, T2a);  T3a = fmaf(oA, wA.w, T3a);
        }
        const float4 tv = make_float4(T0a + T0b, T1a + T1b, T2a + T2b, T3a + T3b);

        // Stage T (lane l -> T[d=l&31, 4p..4p+3]), S, out[n] in this wave's LDS slot.
        *(float4*)&s_T[w * 256 + h * 8 + 4 * p] = tv;
        if (p == 0) {
            s_S[w * 32 + h] = Sa + Sb;
            s_O[w * 32 + h] = outn[(size_t)nu * DIMN + h];
        }
        // Same-wave LDS write->read: compiler-inserted lgkmcnt orders this; no barrier.

        // Contract: lane (h,p) sums its d-half; one shfl_xor combines halves.
        float acc = 0.f;
        const int d0 = p << 4;
        #pragma unroll
        for (int dd = 0; dd < 16; ++dd) {
            const int d = d0 + dd;
            const float4 ta = *(const float4*)&s_T[w * 256 + d * 8];      // broadcast
            const float4 tb = *(const float4*)&s_T[w * 256 + d * 8 + 4];  // broadcast
            const int base = d * 256 + h;                                 // conflict-free
            acc = fmaf(ta.x, s_nnw2[base +   0], acc);
            acc = fmaf(ta.y, s_nnw2[base +  32], acc);
            acc = fmaf(ta.z, s_nnw2[base +  64], acc);
            acc = fmaf(ta.w, s_nnw2[base +  96], acc);
            acc = fmaf(tb.x, s_nnw2[base + 128], acc);
            acc = fmaf(tb.y, s_nnw2[base + 160], acc);
            acc = fmaf(tb.z, s_nnw2[base + 192], acc);
            acc = fmaf(tb.w, s_nnw2[base + 224], acc);
            acc = fmaf(s_S[w * 32 + d], s_nnb[d * 32 + h], acc);   // nn_b term
            acc = fmaf(s_O[w * 32 + d], s_rw [d * 32 + h], acc);   // root term
        }
        acc += __shfl_xor(acc, 32);   // the only cross-lane op per node

        const float v = fmaxf(acc + s_cb[h] + aggfb[(size_t)n * HD + h], 0.f);

        // Run-length pool (batch sorted; uniform across wave).
        const int g = batch[nu];
        if (g != g_cur) {
            if (g_cur >= 0 && p == 0) atomicAdd(u + (size_t)g_cur * HD + h, accp);
            g_cur = g;
            accp = v;
        } else {
            accp += v;
        }
    }
    if (g_cur >= 0 && p == 0) atomicAdd(u + (size_t)g_cur * HD + h, accp);

    // ---- last-block-done: fused head ----
    __threadfence();
    __syncthreads();
    if (tid == 0) {
        const int old = atomicAdd(done, 1);
        s_last = (old == nblocks - 1) ? 1 : 0;
    }
    __syncthreads();
    if (s_last && tid < NG) {
        const int g = tid;
        float ur[HD];
        #pragma unroll
        for (int hh = 0; hh < HD; ++hh)
            ur[hh] = atomicAdd(&u[(size_t)g * HD + hh], 0.f);  // coherent read
        float acc2 = lin2_b[0];
        #pragma unroll
        for (int i = 0; i < 16; ++i) {
            float o = lin1_b[i];
            #pragma unroll
            for (int hh = 0; hh < HD; ++hh)
                o = fmaf(ur[hh], lin1_w[i * HD + hh], o);
            o = fmaxf(o, 0.f);
            acc2 = fmaf(o, lin2_w[i], acc2);
        }
        outp[g] = acc2;
    }
}

extern "C" void kernel_launch(void* const* d_in, const int* in_sizes, int n_in,
                              void* d_out, int out_size, void* d_ws, size_t ws_size,
                              hipStream_t stream)
{
    const float* x      = (const float*)d_in[0];
    const int*   ei     = (const int*)  d_in[1];
    const float* ea     = (const float*)d_in[2];
    const int*   batch  = (const int*)  d_in[3];
    const float* lin0_w = (const float*)d_in[4];
    const float* lin0_b = (const float*)d_in[5];
    const float* nn_w   = (const float*)d_in[6];
    const float* nn_b   = (const float*)d_in[7];
    const float* root_w = (const float*)d_in[8];
    const float* conv_b = (const float*)d_in[9];
    const float* lin1_w = (const float*)d_in[10];
    const float* lin1_b = (const float*)d_in[11];
    const float* lin2_w = (const float*)d_in[12];
    const float* lin2_b = (const float*)d_in[13];

    const int N = in_sizes[0] / FN;   // 12500
    const int E = in_sizes[2] / FE;   // 200000

    float* ws    = (float*)d_ws;
    float* outn  = ws;                           // N*32
    float* aggfb = outn  + (size_t)N * DIMN;     // N*32 (overflow fallback)
    float* u     = aggfb + (size_t)N * DIMN;     // 64*32
    int*   deg   = (int*)(u + (size_t)NG * HD);  // N
    int2*  es    = (int2*)(deg + N);             // N*CAP int2
    int*   done  = (int*)(es + (size_t)N * CAP); // 1

    const int nb1 = (N * DIMN + 255) / 256;      // 1563
    k1_out<<<nb1, 256, 0, stream>>>(x, lin0_w, lin0_b, outn, aggfb, u, deg, done, N);

    const int nbb = (E + 255) / 256;             // 782
    kb_bucket<<<nbb, 256, 0, stream>>>(ei, ea, outn, nn_w, nn_b, deg, es, aggfb, E);

    const int nb3 = (N + K3NPB - 1) / K3NPB;     // 782
    k3_gather<<<nb3, K3T, 0, stream>>>(ea, outn, es, nn_w, nn_b, root_w, conv_b,
                                       deg, aggfb, batch,
                                       lin1_w, lin1_b, lin2_w, lin2_b,
                                       u, done, (float*)d_out, N, nb3);
}

// Round 5
// 166.170 us; speedup vs baseline: 1.5176x; 1.5176x over previous
//
#include <hip/hip_runtime.h>

#define DIMN 32
#define HD   32
#define FN   16
#define FE   8
#define NG   64
#define CAP  64      // bucket capacity (in-degree ~Poisson(16); fallback below)
#define NPW  2       // nodes per wave in K3
#define K3T  512     // threads per block in K3 (8 waves)
#define K3W  (K3T / 64)
#define K3NPB (K3W * NPW)   // 16 nodes per block

// K1: out = relu(x @ lin0_w^T + lin0_b); zero deg/aggfb/u.
__global__ __launch_bounds__(256) void k1_out(
    const float* __restrict__ x, const float* __restrict__ lin0_w,
    const float* __restrict__ lin0_b,
    float* __restrict__ outn, float* __restrict__ aggfb, float* __restrict__ u,
    int* __restrict__ deg, int N)
{
    const int gt = blockIdx.x * 256 + threadIdx.x;
    if (gt >= N * DIMN) return;
    const int n = gt >> 5, d = gt & 31;

    float s = lin0_b[d];
    const float* xr = x + (size_t)n * FN;
    const float* wr = lin0_w + d * FN;
    #pragma unroll
    for (int j = 0; j < FN; ++j) s = fmaf(xr[j], wr[j], s);
    outn[gt] = fmaxf(s, 0.f);

    aggfb[gt] = 0.f;
    if (d == 0) deg[n] = 0;
    if (gt < NG * HD) u[gt] = 0.f;
}

// Kb: bucket edges by destination: es[dst*CAP+pos] = {e, src}.
// Overflow (statistically never for Poisson(16) vs CAP=64): compute the message
// directly and atomicAdd into aggfb, which K3 adds before relu.
__global__ __launch_bounds__(256) void kb_bucket(
    const int* __restrict__ ei, const float* __restrict__ ea,
    const float* __restrict__ outn, const float* __restrict__ nn_w,
    const float* __restrict__ nn_b,
    int* __restrict__ deg, int2* __restrict__ es, float* __restrict__ aggfb, int E)
{
    const int e = blockIdx.x * 256 + threadIdx.x;
    if (e >= E) return;
    const int src = ei[e];
    const int dst = ei[E + e];
    const int pos = atomicAdd(&deg[dst], 1);
    if (pos < CAP) {
        es[(size_t)dst * CAP + pos] = make_int2(e, src);
    } else {
        float ef[FE];
        #pragma unroll
        for (int f = 0; f < FE; ++f) ef[f] = ea[(size_t)e * FE + f];
        for (int h = 0; h < HD; ++h) {
            float m = 0.f;
            for (int d = 0; d < DIMN; ++d) {
                float wdh = nn_b[d * HD + h];
                #pragma unroll
                for (int f = 0; f < FE; ++f)
                    wdh = fmaf(ef[f], nn_w[(d * HD + h) * FE + f], wdh);
                m = fmaf(outn[(size_t)src * DIMN + d], wdh, m);
            }
            atomicAdd(aggfb + (size_t)dst * HD + h, m);
        }
    }
}

// K3: per dst node, accumulate T[d,f] = sum_e out[src,d]*ea[e,f] in registers
// (lane l: d=l&31, f in 4p..4p+3, p=l>>5), stage T/S/out[n] in per-wave LDS,
// contract with LDS-transposed nn_w via broadcast reads, root + relu +
// run-length pool into u. NO threadfence, NO fused head (dispatch-boundary
// visibility is enough for K4).
__global__ __launch_bounds__(K3T) void k3_gather(
    const float* __restrict__ ea, const float* __restrict__ outn,
    const int2* __restrict__ es, const float* __restrict__ nn_w,
    const float* __restrict__ nn_b, const float* __restrict__ root_w,
    const float* __restrict__ conv_b, const int* __restrict__ deg,
    const float* __restrict__ aggfb, const int* __restrict__ batch,
    float* __restrict__ u, int N)
{
    __shared__ float s_nnw2[DIMN * FE * HD];  // [(d*8+f)*32 + h]  32 KB
    __shared__ float s_nnb[DIMN * HD];        // [d*32 + h]         4 KB
    __shared__ float s_rw[DIMN * HD];         // [d*32 + h]         4 KB
    __shared__ float s_cb[HD];
    __shared__ float s_T[K3W * 256];          // per-wave T slot    8 KB
    __shared__ float s_S[K3W * 32];
    __shared__ float s_O[K3W * 32];

    const int tid = threadIdx.x;
    for (int i = tid; i < DIMN * FE * HD; i += K3T) {
        const int d = i >> 8, rem = i & 255, hh = rem >> 3, f = rem & 7;
        s_nnw2[(d * 8 + f) * 32 + hh] = nn_w[i];   // nn_w[i] = nn_w[(d*32+hh)*8+f]
    }
    for (int i = tid; i < DIMN * HD; i += K3T) { s_nnb[i] = nn_b[i]; s_rw[i] = root_w[i]; }
    if (tid < HD) s_cb[tid] = conv_b[tid];
    __syncthreads();

    const int l = tid & 63;
    const int h = l & 31;
    const int p = l >> 5;
    const int w = tid >> 6;
    const int wid   = blockIdx.x * K3W + w;
    const int nbase = wid * NPW;

    float accp  = 0.f;
    int   g_cur = -1;

    for (int i = 0; i < NPW; ++i) {
        const int n = nbase + i;
        if (n >= N) break;                          // n wave-uniform -> whole wave exits
        const int nu = __builtin_amdgcn_readfirstlane(n);
        const int dn = min(deg[nu], CAP);           // uniform -> s_load
        const int2* ep = es + (size_t)nu * CAP;

        // Edge loop: uniform s_load of {e,src}; broadcast-line vector loads; 2-way ILP.
        float T0a = 0.f, T1a = 0.f, T2a = 0.f, T3a = 0.f, Sa = 0.f;
        float T0b = 0.f, T1b = 0.f, T2b = 0.f, T3b = 0.f, Sb = 0.f;
        int j = 0;
        for (; j + 2 <= dn; j += 2) {
            const int2 eA = ep[j];
            const int2 eB = ep[j + 1];
            const float4 wA = *(const float4*)(ea + (size_t)eA.x * FE + 4 * p);
            const float4 wB = *(const float4*)(ea + (size_t)eB.x * FE + 4 * p);
            const float  oA = outn[(size_t)eA.y * DIMN + h];
            const float  oB = outn[(size_t)eB.y * DIMN + h];
            Sa += oA;  Sb += oB;
            T0a = fmaf(oA, wA.x, T0a);  T1a = fmaf(oA, wA.y, T1a);
            T2a = fmaf(oA, wA.z, T2a);  T3a = fmaf(oA, wA.w, T3a);
            T0b = fmaf(oB, wB.x, T0b);  T1b = fmaf(oB, wB.y, T1b);
            T2b = fmaf(oB, wB.z, T2b);  T3b = fmaf(oB, wB.w, T3b);
        }
        if (j < dn) {
            const int2 eA = ep[j];
            const float4 wA = *(const float4*)(ea + (size_t)eA.x * FE + 4 * p);
            const float  oA = outn[(size_t)eA.y * DIMN + h];
            Sa += oA;
            T0a = fmaf(oA, wA.x, T0a);  T1a = fmaf(oA, wA.y, T1a);
            T2a = fmaf(oA, wA.z, T2a);  T3a = fmaf(oA, wA.w, T3a);
        }
        const float4 tv = make_float4(T0a + T0b, T1a + T1b, T2a + T2b, T3a + T3b);

        // Stage T (lane l -> T[d=l&31, 4p..4p+3]), S, out[n] in this wave's LDS slot.
        *(float4*)&s_T[w * 256 + h * 8 + 4 * p] = tv;
        if (p == 0) {
            s_S[w * 32 + h] = Sa + Sb;
            s_O[w * 32 + h] = outn[(size_t)nu * DIMN + h];
        }
        // Same-wave LDS write->read: lockstep wave + compiler lgkmcnt orders this.

        // Contract: lane (h,p) sums its d-half; one shfl_xor combines halves.
        float acc = 0.f;
        const int d0 = p << 4;
        #pragma unroll
        for (int dd = 0; dd < 16; ++dd) {
            const int d = d0 + dd;
            const float4 ta = *(const float4*)&s_T[w * 256 + d * 8];      // broadcast
            const float4 tb = *(const float4*)&s_T[w * 256 + d * 8 + 4];  // broadcast
            const int base = d * 256 + h;                                 // conflict-free
            acc = fmaf(ta.x, s_nnw2[base +   0], acc);
            acc = fmaf(ta.y, s_nnw2[base +  32], acc);
            acc = fmaf(ta.z, s_nnw2[base +  64], acc);
            acc = fmaf(ta.w, s_nnw2[base +  96], acc);
            acc = fmaf(tb.x, s_nnw2[base + 128], acc);
            acc = fmaf(tb.y, s_nnw2[base + 160], acc);
            acc = fmaf(tb.z, s_nnw2[base + 192], acc);
            acc = fmaf(tb.w, s_nnw2[base + 224], acc);
            acc = fmaf(s_S[w * 32 + d], s_nnb[d * 32 + h], acc);   // nn_b term
            acc = fmaf(s_O[w * 32 + d], s_rw [d * 32 + h], acc);   // root term
        }
        acc += __shfl_xor(acc, 32);   // the only cross-lane op per node

        const float v = fmaxf(acc + s_cb[h] + aggfb[(size_t)n * HD + h], 0.f);

        // Run-length pool (batch sorted; uniform across wave).
        const int g = batch[nu];
        if (g != g_cur) {
            if (g_cur >= 0 && p == 0) atomicAdd(u + (size_t)g_cur * HD + h, accp);
            g_cur = g;
            accp = v;
        } else {
            accp += v;
        }
    }
    if (g_cur >= 0 && p == 0) atomicAdd(u + (size_t)g_cur * HD + h, accp);
}

// K4: head — o = relu(u@lin1_w^T + lin1_b); out = o@lin2_w^T + lin2_b.
// Separate dispatch: u atomics are visible at the dispatch boundary (R1/R2-proven).
__global__ __launch_bounds__(64) void k4_head(
    const float* __restrict__ u, const float* __restrict__ lin1_w,
    const float* __restrict__ lin1_b, const float* __restrict__ lin2_w,
    const float* __restrict__ lin2_b, float* __restrict__ outp)
{
    const int g = threadIdx.x;
    if (g >= NG) return;

    float ur[HD];
    #pragma unroll
    for (int hh = 0; hh < HD; ++hh) ur[hh] = u[(size_t)g * HD + hh];

    float acc = lin2_b[0];
    #pragma unroll
    for (int i = 0; i < 16; ++i) {
        float o = lin1_b[i];
        #pragma unroll
        for (int hh = 0; hh < HD; ++hh)
            o = fmaf(ur[hh], lin1_w[i * HD + hh], o);
        o = fmaxf(o, 0.f);
        acc = fmaf(o, lin2_w[i], acc);
    }
    outp[g] = acc;
}

extern "C" void kernel_launch(void* const* d_in, const int* in_sizes, int n_in,
                              void* d_out, int out_size, void* d_ws, size_t ws_size,
                              hipStream_t stream)
{
    const float* x      = (const float*)d_in[0];
    const int*   ei     = (const int*)  d_in[1];
    const float* ea     = (const float*)d_in[2];
    const int*   batch  = (const int*)  d_in[3];
    const float* lin0_w = (const float*)d_in[4];
    const float* lin0_b = (const float*)d_in[5];
    const float* nn_w   = (const float*)d_in[6];
    const float* nn_b   = (const float*)d_in[7];
    const float* root_w = (const float*)d_in[8];
    const float* conv_b = (const float*)d_in[9];
    const float* lin1_w = (const float*)d_in[10];
    const float* lin1_b = (const float*)d_in[11];
    const float* lin2_w = (const float*)d_in[12];
    const float* lin2_b = (const float*)d_in[13];

    const int N = in_sizes[0] / FN;   // 12500
    const int E = in_sizes[2] / FE;   // 200000

    float* ws    = (float*)d_ws;
    float* outn  = ws;                           // N*32
    float* aggfb = outn  + (size_t)N * DIMN;     // N*32 (overflow fallback)
    float* u     = aggfb + (size_t)N * DIMN;     // 64*32
    int*   deg   = (int*)(u + (size_t)NG * HD);  // N
    int2*  es    = (int2*)(deg + N);             // N*CAP int2

    const int nb1 = (N * DIMN + 255) / 256;      // 1563
    k1_out<<<nb1, 256, 0, stream>>>(x, lin0_w, lin0_b, outn, aggfb, u, deg, N);

    const int nbb = (E + 255) / 256;             // 782
    kb_bucket<<<nbb, 256, 0, stream>>>(ei, ea, outn, nn_w, nn_b, deg, es, aggfb, E);

    const int nb3 = (N + K3NPB - 1) / K3NPB;     // 782
    k3_gather<<<nb3, K3T, 0, stream>>>(ea, outn, es, nn_w, nn_b, root_w, conv_b,
                                       deg, aggfb, batch, u, N);

    k4_head<<<1, 64, 0, stream>>>(u, lin1_w, lin1_b, lin2_w, lin2_b, (float*)d_out);
}

// Round 6
// 141.681 us; speedup vs baseline: 1.7800x; 1.1728x over previous
//
#include <hip/hip_runtime.h>

#define DIMN 32
#define HD   32
#define FN   16
#define FE   8
#define NG   64
#define CAP  64          // bucket capacity (in-degree ~Poisson(16); fallback below)
#define K3T  512
#define K3W  (K3T / 64)  // 8 waves = 8 nodes per block (one node per wave)

// K1: out = relu(x @ lin0_w^T + lin0_b); zero deg/aggfb/u.
__global__ __launch_bounds__(256) void k1_out(
    const float* __restrict__ x, const float* __restrict__ lin0_w,
    const float* __restrict__ lin0_b,
    float* __restrict__ outn, float* __restrict__ aggfb, float* __restrict__ u,
    int* __restrict__ deg, int N)
{
    const int gt = blockIdx.x * 256 + threadIdx.x;
    if (gt >= N * DIMN) return;
    const int n = gt >> 5, d = gt & 31;

    float s = lin0_b[d];
    const float* xr = x + (size_t)n * FN;
    const float* wr = lin0_w + d * FN;
    #pragma unroll
    for (int j = 0; j < FN; ++j) s = fmaf(xr[j], wr[j], s);
    outn[gt] = fmaxf(s, 0.f);

    aggfb[gt] = 0.f;
    if (d == 0) deg[n] = 0;
    if (gt < NG * HD) u[gt] = 0.f;
}

// Kb: bucket edges by destination: es[dst*CAP+pos] = {e, src}.
// Overflow (statistically never for Poisson(16) vs CAP=64): compute the message
// directly and atomicAdd into aggfb, which K3 adds before relu.
__global__ __launch_bounds__(256) void kb_bucket(
    const int* __restrict__ ei, const float* __restrict__ ea,
    const float* __restrict__ outn, const float* __restrict__ nn_w,
    const float* __restrict__ nn_b,
    int* __restrict__ deg, int2* __restrict__ es, float* __restrict__ aggfb, int E)
{
    const int e = blockIdx.x * 256 + threadIdx.x;
    if (e >= E) return;
    const int src = ei[e];
    const int dst = ei[E + e];
    const int pos = atomicAdd(&deg[dst], 1);
    if (pos < CAP) {
        es[(size_t)dst * CAP + pos] = make_int2(e, src);
    } else {
        float ef[FE];
        #pragma unroll
        for (int f = 0; f < FE; ++f) ef[f] = ea[(size_t)e * FE + f];
        for (int h = 0; h < HD; ++h) {
            float m = 0.f;
            for (int d = 0; d < DIMN; ++d) {
                float wdh = nn_b[d * HD + h];
                #pragma unroll
                for (int f = 0; f < FE; ++f)
                    wdh = fmaf(ef[f], nn_w[(d * HD + h) * FE + f], wdh);
                m = fmaf(outn[(size_t)src * DIMN + d], wdh, m);
            }
            atomicAdd(aggfb + (size_t)dst * HD + h, m);
        }
    }
}

// One edge's contribution (mask already applied to o).
#define EDGE_FMA(o, a) \
    S  = (S + (o));                      \
    T0 = fmaf((o), (a).x, T0);           \
    T1 = fmaf((o), (a).y, T1);           \
    T2 = fmaf((o), (a).z, T2);           \
    T3 = fmaf((o), (a).w, T3);

// One d-slice of the contraction into accumulator A.
#define CONTRIB(DD, A) { \
    const int d_ = d0 + (DD); \
    const float4 ta_ = *(const float4*)&s_T[w * 256 + d_ * 8]; \
    const float4 tb_ = *(const float4*)&s_T[w * 256 + d_ * 8 + 4]; \
    const float2 so_ = s_SO[w * 32 + d_]; \
    const int b_ = d_ * 256 + h; \
    A = fmaf(ta_.x, s_nnw2[b_      ], A); \
    A = fmaf(ta_.y, s_nnw2[b_ +  32], A); \
    A = fmaf(ta_.z, s_nnw2[b_ +  64], A); \
    A = fmaf(ta_.w, s_nnw2[b_ +  96], A); \
    A = fmaf(tb_.x, s_nnw2[b_ + 128], A); \
    A = fmaf(tb_.y, s_nnw2[b_ + 160], A); \
    A = fmaf(tb_.z, s_nnw2[b_ + 192], A); \
    A = fmaf(tb_.w, s_nnw2[b_ + 224], A); \
    A = fmaf(so_.x, s_nnb[d_ * 32 + h], A); \
    A = fmaf(so_.y, s_rw [d_ * 32 + h], A); }

// K3: one node per wave. Chunk-8 edge loop: 8 uniform s_loads of {e,src} (SGPR),
// then 16 independent vector loads in flight, then FMAs. T staged per-wave in LDS,
// contraction against LDS-transposed nn_w (conflict-free), block-level pooling.
__global__ __launch_bounds__(K3T, 8) void k3_gather(
    const float* __restrict__ ea, const float* __restrict__ outn,
    const int2* __restrict__ es, const float* __restrict__ nn_w,
    const float* __restrict__ nn_b, const float* __restrict__ root_w,
    const float* __restrict__ conv_b, const int* __restrict__ deg,
    const float* __restrict__ aggfb, const int* __restrict__ batch,
    float* __restrict__ u, int N)
{
    __shared__ float  s_nnw2[DIMN * FE * HD];  // [(d*8+f)*32 + h]  32 KB
    __shared__ float  s_nnb[DIMN * HD];        // 4 KB
    __shared__ float  s_rw[DIMN * HD];         // 4 KB
    __shared__ float  s_cb[HD];
    __shared__ float  s_T[K3W * 256];          // 8 KB (per-wave T slot)
    __shared__ float2 s_SO[K3W * 32];          // 2 KB (S, out[n]) per wave
    __shared__ float  s_V[K3W * 32];           // 1 KB (per-wave node result)
    __shared__ int    s_G[K3W];

    const int tid = threadIdx.x;
    for (int i = tid; i < DIMN * FE * HD; i += K3T) {
        const int d = i >> 8, rem = i & 255, hh = rem >> 3, f = rem & 7;
        s_nnw2[(d * 8 + f) * 32 + hh] = nn_w[i];   // nn_w[i] = nn_w[(d*32+hh)*8+f]
    }
    for (int i = tid; i < DIMN * HD; i += K3T) { s_nnb[i] = nn_b[i]; s_rw[i] = root_w[i]; }
    if (tid < HD) s_cb[tid] = conv_b[tid];
    __syncthreads();

    const int l = tid & 63;
    const int h = l & 31;
    const int p = l >> 5;
    const int w = tid >> 6;
    const int n = blockIdx.x * K3W + w;   // one node per wave

    int gval = -1;
    if (n < N) {
        const int nu = __builtin_amdgcn_readfirstlane(n);
        const int dn = min(deg[nu], CAP);          // uniform -> s_load
        const int2* ep = es + (size_t)nu * CAP;
        const int f0 = 4 * p;

        float T0 = 0.f, T1 = 0.f, T2 = 0.f, T3 = 0.f, S = 0.f;

        for (int j0 = 0; j0 < dn; j0 += 8) {
            const int jm = dn - 1;
            // 8 uniform index loads (SGPR), clamped for the tail.
            const int2 E0 = ep[j0];
            const int2 E1 = ep[min(j0 + 1, jm)];
            const int2 E2 = ep[min(j0 + 2, jm)];
            const int2 E3 = ep[min(j0 + 3, jm)];
            const int2 E4 = ep[min(j0 + 4, jm)];
            const int2 E5 = ep[min(j0 + 5, jm)];
            const int2 E6 = ep[min(j0 + 6, jm)];
            const int2 E7 = ep[min(j0 + 7, jm)];

            // 16 independent vector loads, all in flight together.
            const float4 a0 = *(const float4*)(ea + (size_t)E0.x * FE + f0);
            const float4 a1 = *(const float4*)(ea + (size_t)E1.x * FE + f0);
            const float4 a2 = *(const float4*)(ea + (size_t)E2.x * FE + f0);
            const float4 a3 = *(const float4*)(ea + (size_t)E3.x * FE + f0);
            const float4 a4 = *(const float4*)(ea + (size_t)E4.x * FE + f0);
            const float4 a5 = *(const float4*)(ea + (size_t)E5.x * FE + f0);
            const float4 a6 = *(const float4*)(ea + (size_t)E6.x * FE + f0);
            const float4 a7 = *(const float4*)(ea + (size_t)E7.x * FE + f0);
            float o0 = outn[(size_t)E0.y * DIMN + h];
            float o1 = outn[(size_t)E1.y * DIMN + h];
            float o2 = outn[(size_t)E2.y * DIMN + h];
            float o3 = outn[(size_t)E3.y * DIMN + h];
            float o4 = outn[(size_t)E4.y * DIMN + h];
            float o5 = outn[(size_t)E5.y * DIMN + h];
            float o6 = outn[(size_t)E6.y * DIMN + h];
            float o7 = outn[(size_t)E7.y * DIMN + h];

            // Zero-mask clamped tail edges (uniform conditions -> cndmask).
            o1 = (j0 + 1 <= jm) ? o1 : 0.f;
            o2 = (j0 + 2 <= jm) ? o2 : 0.f;
            o3 = (j0 + 3 <= jm) ? o3 : 0.f;
            o4 = (j0 + 4 <= jm) ? o4 : 0.f;
            o5 = (j0 + 5 <= jm) ? o5 : 0.f;
            o6 = (j0 + 6 <= jm) ? o6 : 0.f;
            o7 = (j0 + 7 <= jm) ? o7 : 0.f;

            EDGE_FMA(o0, a0) EDGE_FMA(o1, a1) EDGE_FMA(o2, a2) EDGE_FMA(o3, a3)
            EDGE_FMA(o4, a4) EDGE_FMA(o5, a5) EDGE_FMA(o6, a6) EDGE_FMA(o7, a7)
        }

        // Stage T (lane l -> T[d=h, f0..f0+3]), (S, out[n,d]) for the contraction.
        *(float4*)&s_T[w * 256 + h * 8 + f0] = make_float4(T0, T1, T2, T3);
        if (p == 0) s_SO[w * 32 + h] = make_float2(S, outn[(size_t)nu * DIMN + h]);
        // Same-wave LDS write->read: lockstep + compiler lgkmcnt orders this.

        const float base = aggfb[(size_t)nu * HD + h] + s_cb[h];

        // Contraction: lane (h,p) sums its 16-d half; 4 split accumulator chains.
        float acc0 = 0.f, acc1 = 0.f, acc2 = 0.f, acc3 = 0.f;
        const int d0 = p << 4;
        #pragma unroll
        for (int dd = 0; dd < 16; dd += 4) {
            CONTRIB(dd + 0, acc0)
            CONTRIB(dd + 1, acc1)
            CONTRIB(dd + 2, acc2)
            CONTRIB(dd + 3, acc3)
        }
        float acc = (acc0 + acc1) + (acc2 + acc3);
        acc += __shfl_xor(acc, 32);              // combine the two half-wave d-halves

        const float v = fmaxf(acc + base, 0.f);
        if (p == 0) s_V[w * 32 + h] = v;
        gval = batch[nu];                        // uniform across the wave
    }
    if (l == 0) s_G[w] = gval;
    __syncthreads();

    // Block-level run-length pool over the 8 consecutive nodes (batch sorted):
    // ~1-2 atomic flushes per block instead of one per wave.
    if (tid < 32) {
        float accp = 0.f;
        int   gc   = -1;
        #pragma unroll
        for (int ww = 0; ww < K3W; ++ww) {
            const int gg = s_G[ww];
            if (gg >= 0) {
                const float vv = s_V[ww * 32 + tid];
                if (gg != gc) {
                    if (gc >= 0) atomicAdd(u + (size_t)gc * HD + tid, accp);
                    gc = gg;
                    accp = vv;
                } else {
                    accp += vv;
                }
            }
        }
        if (gc >= 0) atomicAdd(u + (size_t)gc * HD + tid, accp);
    }
}

// K4: head — o = relu(u@lin1_w^T + lin1_b); out = o@lin2_w^T + lin2_b.
// Separate dispatch: u atomics are visible at the dispatch boundary.
__global__ __launch_bounds__(64) void k4_head(
    const float* __restrict__ u, const float* __restrict__ lin1_w,
    const float* __restrict__ lin1_b, const float* __restrict__ lin2_w,
    const float* __restrict__ lin2_b, float* __restrict__ outp)
{
    const int g = threadIdx.x;
    if (g >= NG) return;

    float ur[HD];
    #pragma unroll
    for (int hh = 0; hh < HD; ++hh) ur[hh] = u[(size_t)g * HD + hh];

    float acc = lin2_b[0];
    #pragma unroll
    for (int i = 0; i < 16; ++i) {
        float o = lin1_b[i];
        #pragma unroll
        for (int hh = 0; hh < HD; ++hh)
            o = fmaf(ur[hh], lin1_w[i * HD + hh], o);
        o = fmaxf(o, 0.f);
        acc = fmaf(o, lin2_w[i], acc);
    }
    outp[g] = acc;
}

extern "C" void kernel_launch(void* const* d_in, const int* in_sizes, int n_in,
                              void* d_out, int out_size, void* d_ws, size_t ws_size,
                              hipStream_t stream)
{
    const float* x      = (const float*)d_in[0];
    const int*   ei     = (const int*)  d_in[1];
    const float* ea     = (const float*)d_in[2];
    const int*   batch  = (const int*)  d_in[3];
    const float* lin0_w = (const float*)d_in[4];
    const float* lin0_b = (const float*)d_in[5];
    const float* nn_w   = (const float*)d_in[6];
    const float* nn_b   = (const float*)d_in[7];
    const float* root_w = (const float*)d_in[8];
    const float* conv_b = (const float*)d_in[9];
    const float* lin1_w = (const float*)d_in[10];
    const float* lin1_b = (const float*)d_in[11];
    const float* lin2_w = (const float*)d_in[12];
    const float* lin2_b = (const float*)d_in[13];

    const int N = in_sizes[0] / FN;   // 12500
    const int E = in_sizes[2] / FE;   // 200000

    float* ws    = (float*)d_ws;
    float* outn  = ws;                           // N*32
    float* aggfb = outn  + (size_t)N * DIMN;     // N*32 (overflow fallback)
    float* u     = aggfb + (size_t)N * DIMN;     // 64*32
    int*   deg   = (int*)(u + (size_t)NG * HD);  // N
    int2*  es    = (int2*)(deg + N);             // N*CAP int2 (8B-aligned)

    const int nb1 = (N * DIMN + 255) / 256;      // 1563
    k1_out<<<nb1, 256, 0, stream>>>(x, lin0_w, lin0_b, outn, aggfb, u, deg, N);

    const int nbb = (E + 255) / 256;             // 782
    kb_bucket<<<nbb, 256, 0, stream>>>(ei, ea, outn, nn_w, nn_b, deg, es, aggfb, E);

    const int nb3 = (N + K3W - 1) / K3W;         // 1563 (8 nodes / block)
    k3_gather<<<nb3, K3T, 0, stream>>>(ea, outn, es, nn_w, nn_b, root_w, conv_b,
                                       deg, aggfb, batch, u, N);

    k4_head<<<1, 64, 0, stream>>>(u, lin1_w, lin1_b, lin2_w, lin2_b, (float*)d_out);
}